// Round 1
// baseline (660.953 us; speedup 1.0000x reference)
//
#include <hip/hip_runtime.h>
#include <hip/hip_bf16.h>
#include <cstdint>

typedef __attribute__((ext_vector_type(8))) short short8;
typedef __attribute__((ext_vector_type(4))) float f32x4;

constexpr int B_ = 2048, E_ = 16, D_ = 1536, H_ = 1024;
constexpr int NHEAD = 256;  // padded head dim: 36(s)+36(o)+132(p)=204 -> 256
constexpr float EPS_ = 2.220446049250313e-16f;

__device__ __forceinline__ void gload_lds16(const void* g, void* l) {
  __builtin_amdgcn_global_load_lds((const __attribute__((address_space(1))) void*)g,
                                   (__attribute__((address_space(3))) void*)l,
                                   16, 0, 0);
}

// ---------------- pack x (concat) to bf16 ----------------
__global__ __launch_bounds__(256) void pack_x(
    const float* __restrict__ sf, const float* __restrict__ of_,
    const float* __restrict__ ppf, const float* __restrict__ pvf,
    __hip_bfloat16* __restrict__ xb)
{
  const int b = blockIdx.x;
  for (int d = threadIdx.x; d < D_; d += 256) {
    float v;
    if (d < 512)       v = sf[b * 512 + d];
    else if (d < 1024) v = of_[b * 512 + (d - 512)];
    else if (d < 1280) v = ppf[b * 256 + (d - 1024)];
    else               v = pvf[b * 256 + (d - 1280)];
    xb[(size_t)b * D_ + d] = __float2bfloat16(v);
  }
}

// ---------------- gating: fp32, top-4 + softmax ----------------
__global__ __launch_bounds__(256) void gate_kernel(
    const float* __restrict__ sf, const float* __restrict__ of_,
    const float* __restrict__ ppf, const float* __restrict__ pvf,
    const float* __restrict__ wg, const float* __restrict__ wn,
    const float* __restrict__ noise,
    int* __restrict__ topidx, float* __restrict__ topw)
{
  __shared__ float xs[D_];
  __shared__ float sums[32];
  const int b = blockIdx.x, t = threadIdx.x;
  for (int d = t; d < D_; d += 256) {
    float v;
    if (d < 512)       v = sf[b * 512 + d];
    else if (d < 1024) v = of_[b * 512 + (d - 512)];
    else if (d < 1280) v = ppf[b * 256 + (d - 1024)];
    else               v = pvf[b * 256 + (d - 1280)];
    xs[d] = v;
  }
  __syncthreads();
  const int job = t >> 3, sub = t & 7;   // 32 jobs (16 gate + 16 noise), 8 lanes each
  const int e = job & 15;
  const float* w = (job < 16) ? wg : wn;
  float p = 0.f;
  for (int d = sub; d < D_; d += 8) p += xs[d] * w[d * 16 + e];
  p += __shfl_down(p, 4, 8);
  p += __shfl_down(p, 2, 8);
  p += __shfl_down(p, 1, 8);
  if (sub == 0) sums[job] = p;
  __syncthreads();
  if (t == 0) {
    float lg[16];
    for (int i = 0; i < 16; ++i) {
      float z = sums[16 + i];
      float sp = (z > 0.f) ? (z + log1pf(expf(-z))) : log1pf(expf(z));  // softplus
      lg[i] = sums[i] + noise[b * 16 + i] * (sp + 1e-2f);
    }
    float tv[4]; int ti[4];
    unsigned used = 0;
    for (int k = 0; k < 4; ++k) {
      float best = -INFINITY; int bi = 0;
      for (int i = 0; i < 16; ++i)
        if (!((used >> i) & 1u) && lg[i] > best) { best = lg[i]; bi = i; }
      used |= 1u << bi; tv[k] = best; ti[k] = bi;
    }
    float s = 0.f, ex[4];
    for (int k = 0; k < 4; ++k) { ex[k] = expf(tv[k] - tv[0]); s += ex[k]; }
    for (int k = 0; k < 4; ++k) { topw[b * 4 + k] = ex[k] / s; topidx[b * 4 + k] = ti[k]; }
  }
}

// ---------------- tiled transpose f32[K][N] -> bf16[N][K], per expert ----------------
__global__ __launch_bounds__(256) void transpose_bf16(
    const float* __restrict__ src, __hip_bfloat16* __restrict__ dst, int K, int N)
{
  __shared__ float tile[32][33];
  const int e = blockIdx.z;
  const int n0 = blockIdx.x * 32, k0 = blockIdx.y * 32;
  const int tx = threadIdx.x, ty = threadIdx.y;
  const float* s = src + (size_t)e * K * N;
  __hip_bfloat16* d = dst + (size_t)e * N * K;
#pragma unroll
  for (int r = 0; r < 4; ++r) {
    const int k = k0 + ty + r * 8;
    tile[ty + r * 8][tx] = s[(size_t)k * N + n0 + tx];
  }
  __syncthreads();
#pragma unroll
  for (int r = 0; r < 4; ++r) {
    const int n = n0 + ty + r * 8;
    d[(size_t)n * K + k0 + tx] = __float2bfloat16(tile[tx][ty + r * 8]);
  }
}

// heads: Ws/Wo/Wp [E][H][{36,36,132}] -> WhT [E][256][H], rows 204..255 zero
__global__ __launch_bounds__(256) void head_transpose(
    const float* __restrict__ Wsp, const float* __restrict__ Wop,
    const float* __restrict__ Wpp, __hip_bfloat16* __restrict__ dst)
{
  __shared__ float tile[32][33];
  const int e = blockIdx.z;
  const int k0 = blockIdx.x * 32;  // over H
  const int n0 = blockIdx.y * 32;  // over padded class dim
  const int tx = threadIdx.x, ty = threadIdx.y;
#pragma unroll
  for (int r = 0; r < 4; ++r) {
    const int k = k0 + ty + r * 8;
    const int n = n0 + tx;
    float v;
    if (n < 36)       v = Wsp[((size_t)e * H_ + k) * 36 + n];
    else if (n < 72)  v = Wop[((size_t)e * H_ + k) * 36 + (n - 36)];
    else if (n < 204) v = Wpp[((size_t)e * H_ + k) * 132 + (n - 72)];
    else              v = 0.f;
    tile[ty + r * 8][tx] = v;
  }
  __syncthreads();
#pragma unroll
  for (int r = 0; r < 4; ++r) {
    const int n = n0 + ty + r * 8;
    dst[((size_t)e * NHEAD + n) * H_ + k0 + tx] = __float2bfloat16(tile[tx][ty + r * 8]);
  }
}

__global__ __launch_bounds__(256) void pack_hbias(
    const float* __restrict__ bs, const float* __restrict__ bo,
    const float* __restrict__ bp, float* __restrict__ hb)
{
  const int e = blockIdx.x, t = threadIdx.x;
  float v = 0.f;
  if (t < 36)       v = bs[e * 36 + t];
  else if (t < 72)  v = bo[e * 36 + (t - 36)];
  else if (t < 204) v = bp[e * 132 + (t - 72)];
  hb[e * NHEAD + t] = v;
}

// ---------------- batched GEMM: C[e] = A[e][M,K] * B[e][N,K]^T, m97 structure ----------
// BM=BN=128, BK=64, 256 threads (2x2 waves, each 64x64 out via 4x4 16x16x32 MFMA frags)
// EPI==0: relu(acc+bias) -> bf16 ; EPI==1: acc+bias -> f32
template <int EPI>
__global__ __launch_bounds__(256) void gemm_bt(
    const __hip_bfloat16* __restrict__ A, size_t strideA, int ldA,
    const __hip_bfloat16* __restrict__ Bm, size_t strideB,
    const float* __restrict__ bias,
    void* __restrict__ Cout, size_t strideC, int ldC,
    int K)
{
  __shared__ __align__(16) __hip_bfloat16 lA[128 * 64];
  __shared__ __align__(16) __hip_bfloat16 lB[128 * 64];
  const int e = blockIdx.z;
  const int bm = blockIdx.x, bn = blockIdx.y;
  const int t = threadIdx.x;
  const int w = t >> 6, lane = t & 63;
  const int wm = w >> 1, wn = w & 1;
  const __hip_bfloat16* Ae = A + (size_t)e * strideA + (size_t)(bm * 128) * ldA;
  const __hip_bfloat16* Be = Bm + (size_t)e * strideB + (size_t)(bn * 128) * K;
  const int rsub = lane >> 3;         // 0..7  row within wave's 8-row staging slab
  const int csub = (lane & 7) * 8;    // 0..56 bf16 col offset (16B chunks)

  f32x4 acc[4][4];
#pragma unroll
  for (int m = 0; m < 4; ++m)
#pragma unroll
    for (int n = 0; n < 4; ++n) acc[m][n] = (f32x4){0.f, 0.f, 0.f, 0.f};

  const int KT = K >> 6;
  const int arow = wm * 64 + (lane & 15);
  const int brow = wn * 64 + (lane & 15);
  const int khalf = (lane >> 4) * 8;

  for (int kt = 0; kt < KT; ++kt) {
    const int k0 = kt << 6;
    __syncthreads();  // previous tile's compute done before overwrite
#pragma unroll
    for (int j = 0; j < 4; ++j) {
      const int r = j * 32 + w * 8 + rsub;
      gload_lds16(Ae + (size_t)r * ldA + (k0 + csub), &lA[j * 2048 + w * 512]);
      gload_lds16(Be + (size_t)r * K + (k0 + csub), &lB[j * 2048 + w * 512]);
    }
    asm volatile("s_waitcnt vmcnt(0)" ::: "memory");
    __syncthreads();
#pragma unroll
    for (int kk = 0; kk < 2; ++kk) {
      short8 af[4], bfr[4];
#pragma unroll
      for (int m = 0; m < 4; ++m)
        af[m] = *(const short8*)&lA[(arow + m * 16) * 64 + kk * 32 + khalf];
#pragma unroll
      for (int n = 0; n < 4; ++n)
        bfr[n] = *(const short8*)&lB[(brow + n * 16) * 64 + kk * 32 + khalf];
#pragma unroll
      for (int m = 0; m < 4; ++m)
#pragma unroll
        for (int n = 0; n < 4; ++n)
          acc[m][n] = __builtin_amdgcn_mfma_f32_16x16x32_bf16(af[m], bfr[n], acc[m][n], 0, 0, 0);
    }
  }

  // epilogue: C/D layout col=lane&15, row=(lane>>4)*4+j
  const int rbase = (lane >> 4) * 4, cbase = lane & 15;
#pragma unroll
  for (int n = 0; n < 4; ++n) {
    const int gcol = bn * 128 + wn * 64 + n * 16 + cbase;
    const float bv = bias[(size_t)e * ldC + gcol];
#pragma unroll
    for (int m = 0; m < 4; ++m) {
      const int grow = bm * 128 + wm * 64 + m * 16 + rbase;
#pragma unroll
      for (int j = 0; j < 4; ++j) {
        float v = acc[m][n][j] + bv;
        const size_t idx = (size_t)e * strideC + (size_t)(grow + j) * ldC + gcol;
        if (EPI == 0) {
          ((__hip_bfloat16*)Cout)[idx] = __float2bfloat16(v > 0.f ? v : 0.f);
        } else {
          ((float*)Cout)[idx] = v;
        }
      }
    }
  }
}

// ---------------- fused log-softmax + combine over the token's 4 experts ------------
__global__ __launch_bounds__(256) void combine_kernel(
    const float* __restrict__ logits, const int* __restrict__ topidx,
    const float* __restrict__ topw, float* __restrict__ out)
{
  __shared__ float rows[4][204];
  __shared__ float lse[4][3];
  __shared__ float wk[4];
  const int b = blockIdx.x, t = threadIdx.x;
  if (t < 4) wk[t] = topw[b * 4 + t];
#pragma unroll
  for (int k = 0; k < 4; ++k) {
    const int e = topidx[b * 4 + k];
    if (t < 204) rows[k][t] = logits[((size_t)e * B_ + b) * NHEAD + t];
  }
  __syncthreads();
  const int wv = t >> 6, lane = t & 63;  // wave wv handles expert slot wv
  const int segbase[3] = {0, 36, 72};
  const int segcnt[3] = {36, 36, 132};
  for (int s = 0; s < 3; ++s) {
    float mx = -INFINITY;
    for (int c = lane; c < segcnt[s]; c += 64) mx = fmaxf(mx, rows[wv][segbase[s] + c]);
    for (int o = 32; o > 0; o >>= 1) mx = fmaxf(mx, __shfl_xor(mx, o));
    float sum = 0.f;
    for (int c = lane; c < segcnt[s]; c += 64) sum += expf(rows[wv][segbase[s] + c] - mx);
    for (int o = 32; o > 0; o >>= 1) sum += __shfl_xor(sum, o);
    if (lane == 0) lse[wv][s] = mx + logf(sum);
  }
  __syncthreads();
  if (t < 204) {
    const int seg = t < 36 ? 0 : (t < 72 ? 1 : 2);
    float acc = 0.f;
    for (int k = 0; k < 4; ++k) acc += wk[k] * expf(rows[k][t] - lse[k][seg]);
    if (acc == 0.f) acc = EPS_;
    const float r = logf(acc);
    if (t < 36)      out[b * 36 + t] = r;
    else if (t < 72) out[73728 + b * 36 + (t - 36)] = r;
    else             out[147456 + b * 132 + (t - 72)] = r;
  }
}

extern "C" void kernel_launch(void* const* d_in, const int* in_sizes, int n_in,
                              void* d_out, int out_size, void* d_ws, size_t ws_size,
                              hipStream_t stream)
{
  (void)in_sizes; (void)n_in; (void)out_size; (void)ws_size;
  const float* sf      = (const float*)d_in[0];
  const float* of_     = (const float*)d_in[1];
  const float* ppf     = (const float*)d_in[2];
  const float* pvf     = (const float*)d_in[3];
  const float* w_gate  = (const float*)d_in[4];
  const float* w_noise = (const float*)d_in[5];
  const float* W1      = (const float*)d_in[6];
  const float* b1      = (const float*)d_in[7];
  const float* W2      = (const float*)d_in[8];
  const float* b2      = (const float*)d_in[9];
  const float* Ws      = (const float*)d_in[10];
  const float* bs      = (const float*)d_in[11];
  const float* Wo      = (const float*)d_in[12];
  const float* bo      = (const float*)d_in[13];
  const float* Wp      = (const float*)d_in[14];
  const float* bp      = (const float*)d_in[15];
  const float* noise   = (const float*)d_in[16];

  char* ws = (char*)d_ws;
  size_t off = 0;
  auto take = [&](size_t bytes) -> void* {
    void* p = ws + off; off += (bytes + 255) & ~(size_t)255; return p;
  };
  __hip_bfloat16* xb  = (__hip_bfloat16*)take((size_t)B_ * D_ * 2);            // 6.3 MB
  __hip_bfloat16* W1T = (__hip_bfloat16*)take((size_t)E_ * H_ * D_ * 2);       // 50.3 MB
  __hip_bfloat16* W2T = (__hip_bfloat16*)take((size_t)E_ * H_ * H_ * 2);       // 33.6 MB
  __hip_bfloat16* WhT = (__hip_bfloat16*)take((size_t)E_ * NHEAD * H_ * 2);    // 8.4 MB
  float* hbias        = (float*)take((size_t)E_ * NHEAD * 4);
  __hip_bfloat16* h1  = (__hip_bfloat16*)take((size_t)E_ * B_ * H_ * 2);       // 67.1 MB
  __hip_bfloat16* h2  = (__hip_bfloat16*)take((size_t)E_ * B_ * H_ * 2);       // 67.1 MB
  int* topidx         = (int*)take((size_t)B_ * 4 * 4);
  float* topw         = (float*)take((size_t)B_ * 4 * 4);
  float* logits       = (float*)h1;  // alias: h1 dead once GEMM2 completes (33.6 MB used)

  pack_x<<<B_, 256, 0, stream>>>(sf, of_, ppf, pvf, xb);
  gate_kernel<<<B_, 256, 0, stream>>>(sf, of_, ppf, pvf, w_gate, w_noise, noise, topidx, topw);
  transpose_bf16<<<dim3(H_ / 32, D_ / 32, E_), dim3(32, 8), 0, stream>>>(W1, W1T, D_, H_);
  transpose_bf16<<<dim3(H_ / 32, H_ / 32, E_), dim3(32, 8), 0, stream>>>(W2, W2T, H_, H_);
  head_transpose<<<dim3(H_ / 32, NHEAD / 32, E_), dim3(32, 8), 0, stream>>>(Ws, Wo, Wp, WhT);
  pack_hbias<<<E_, 256, 0, stream>>>(bs, bo, bp, hbias);

  gemm_bt<0><<<dim3(B_ / 128, H_ / 128, E_), 256, 0, stream>>>(
      xb, 0, D_, W1T, (size_t)H_ * D_, b1, h1, (size_t)B_ * H_, H_, D_);
  gemm_bt<0><<<dim3(B_ / 128, H_ / 128, E_), 256, 0, stream>>>(
      h1, (size_t)B_ * H_, H_, W2T, (size_t)H_ * H_, b2, h2, (size_t)B_ * H_, H_, H_);
  gemm_bt<1><<<dim3(B_ / 128, NHEAD / 128, E_), 256, 0, stream>>>(
      h2, (size_t)B_ * H_, H_, WhT, (size_t)NHEAD * H_, hbias, logits, (size_t)B_ * NHEAD, NHEAD, H_);

  combine_kernel<<<B_, 256, 0, stream>>>(logits, topidx, topw, (float*)d_out);
}